// Round 2
// baseline (416.278 us; speedup 1.0000x reference)
//
#include <hip/hip_runtime.h>
#include <hip/hip_bf16.h>
#include <stdint.h>
#include <stddef.h>

#define NB 16
#define NS 1024
#define ND 512
#define NH 8
#define NDK 64
#define NDV 64
#define NDFF 2048
#define NTOK (NB * NS)

typedef __bf16 bf16;
typedef __attribute__((ext_vector_type(2))) __bf16 bf16x2;
typedef __attribute__((ext_vector_type(4))) __bf16 bf16x4;
typedef __attribute__((ext_vector_type(8))) __bf16 bf16x8;
typedef __attribute__((ext_vector_type(4))) float f32x4;

__device__ __forceinline__ void async_copy16(const void* g, void* l) {
  __builtin_amdgcn_global_load_lds(
      (const __attribute__((address_space(1))) void*)g,
      (__attribute__((address_space(3))) void*)l,
      16, 0, 0);
}

// ---------------- fp32 -> bf16 conversion ----------------
__global__ __launch_bounds__(256) void cvt_f32_bf16(const float* __restrict__ in,
                                                    bf16* __restrict__ out, int n4) {
  int i = blockIdx.x * 256 + threadIdx.x;
  if (i >= n4) return;
  const float4 v = ((const float4*)in)[i];
  bf16x4 o = {(bf16)v.x, (bf16)v.y, (bf16)v.z, (bf16)v.w};
  ((bf16x4*)out)[i] = o;
}

// ---------------- GEMM: C[M,N] = A[M,K] @ Bw[N,K]^T + bias (+resid) ----------------
// 128x128 tile, BK=32, 256 threads (4 waves in 2x2), mfma_f32_16x16x32_bf16.
template <bool RELU, bool RESID, bool OUTB, bool OUTF>
__global__ __launch_bounds__(256) void gemm_bt(
    const bf16* __restrict__ A, const bf16* __restrict__ Bw,
    const float* __restrict__ bias, const float* __restrict__ resid,
    bf16* __restrict__ Cb, float* __restrict__ Cf,
    int M, int N, int K) {
  __shared__ bf16 As[128 * 32];
  __shared__ bf16 Bs[128 * 32];
  const int tid = threadIdx.x;
  const int lane = tid & 63;
  const int wid = tid >> 6;
  const int tm = blockIdx.y, tn = blockIdx.x;
  const int wm = wid >> 1, wn = wid & 1;
  const int lr = lane & 15, lk = (lane >> 4) * 8;
  const int srow = lane >> 2, scol = (lane & 3) * 8;

  f32x4 acc[4][4] = {};

  const bf16* Abase = A + (size_t)(tm * 128 + srow) * K + scol;
  const bf16* Bbase = Bw + (size_t)(tn * 128 + srow) * K + scol;
  const int kiters = K >> 5;

  for (int kb = 0; kb < kiters; ++kb) {
    __syncthreads();
#pragma unroll
    for (int s2 = 0; s2 < 2; ++s2) {
      const int seg = wid * 2 + s2;
      async_copy16(Abase + (size_t)seg * 16 * K + kb * 32, &As[seg * 512]);
      async_copy16(Bbase + (size_t)seg * 16 * K + kb * 32, &Bs[seg * 512]);
    }
    __syncthreads();
    bf16x8 af[4], bfr[4];
#pragma unroll
    for (int i = 0; i < 4; ++i)
      af[i] = *(const bf16x8*)&As[(wm * 64 + i * 16 + lr) * 32 + lk];
#pragma unroll
    for (int j = 0; j < 4; ++j)
      bfr[j] = *(const bf16x8*)&Bs[(wn * 64 + j * 16 + lr) * 32 + lk];
#pragma unroll
    for (int i = 0; i < 4; ++i)
#pragma unroll
      for (int j = 0; j < 4; ++j)
        acc[i][j] = __builtin_amdgcn_mfma_f32_16x16x32_bf16(af[i], bfr[j], acc[i][j], 0, 0, 0);
  }

#pragma unroll
  for (int i = 0; i < 4; ++i) {
    const int row0 = tm * 128 + wm * 64 + i * 16 + (lane >> 4) * 4;
#pragma unroll
    for (int j = 0; j < 4; ++j) {
      const int col = tn * 128 + wn * 64 + j * 16 + lr;
      const float bcol = bias[col];
#pragma unroll
      for (int r = 0; r < 4; ++r) {
        float c = acc[i][j][r] + bcol;
        if (RESID) c += resid[(size_t)(row0 + r) * N + col];
        if (RELU) c = fmaxf(c, 0.f);
        if (OUTB) Cb[(size_t)(row0 + r) * N + col] = (bf16)c;
        if (OUTF) Cf[(size_t)(row0 + r) * N + col] = c;
      }
    }
  }
}

// ---------------- LayerNorm (one block per row of 512) ----------------
__global__ __launch_bounds__(256) void layernorm_k(
    const float* __restrict__ in, const float* __restrict__ gam,
    const float* __restrict__ bet, float eps,
    float* __restrict__ outf, bf16* __restrict__ outb) {
  const int row = blockIdx.x;
  const int t = threadIdx.x;
  const float2 v = ((const float2*)(in + (size_t)row * ND))[t];
  float s = v.x + v.y;
  float s2 = v.x * v.x + v.y * v.y;
#pragma unroll
  for (int off = 32; off > 0; off >>= 1) {
    s += __shfl_down(s, off, 64);
    s2 += __shfl_down(s2, off, 64);
  }
  __shared__ float red[8];
  const int wid = t >> 6, lane = t & 63;
  if (lane == 0) { red[wid] = s; red[4 + wid] = s2; }
  __syncthreads();
  const float a = red[0] + red[1] + red[2] + red[3];
  const float b = red[4] + red[5] + red[6] + red[7];
  const float mu = a * (1.f / ND);
  const float var = b * (1.f / ND) - mu * mu;
  const float rstd = rsqrtf(var + eps);
  const float2 g2 = ((const float2*)gam)[t];
  const float2 b2 = ((const float2*)bet)[t];
  const float o0 = (v.x - mu) * rstd * g2.x + b2.x;
  const float o1 = (v.y - mu) * rstd * g2.y + b2.y;
  if (outf) ((float2*)(outf + (size_t)row * ND))[t] = make_float2(o0, o1);
  if (outb) {
    bf16x2 ob = {(bf16)o0, (bf16)o1};
    ((bf16x2*)(outb + (size_t)row * ND))[t] = ob;
  }
}

// ---------------- Flash attention, causal with diagonal -current ----------------
// grid: (S/64, B*H); 256 threads = 4 waves, wave w handles q rows [q0+16w, q0+16w+16)
__global__ __launch_bounds__(256) void attn_k(
    const bf16* __restrict__ Q, const bf16* __restrict__ Kg,
    const bf16* __restrict__ V, bf16* __restrict__ O,
    const int* __restrict__ curp) {
  const int current = *curp;
  const int b = blockIdx.y >> 3;
  const int h = blockIdx.y & 7;
  const int q0 = blockIdx.x * 64;
  const int tid = threadIdx.x, lane = tid & 63, wid = tid >> 6;
  const int lr = lane & 15, lk = (lane >> 4) * 8;

  __shared__ bf16 Kt[64 * 72];
  __shared__ bf16 Vt[64 * 72];        // transposed: Vt[dv][key]
  __shared__ bf16 Pw[4][16 * 72];

  const size_t qoff = (size_t)(b * NS + q0 + wid * 16 + lr) * ND + h * 64 + lk;
  const bf16x8 aq0 = *(const bf16x8*)&Q[qoff];
  const bf16x8 aq1 = *(const bf16x8*)&Q[qoff + 32];

  f32x4 acc[4] = {};
  float m_run[4] = {-1e30f, -1e30f, -1e30f, -1e30f};
  float l_run[4] = {0.f, 0.f, 0.f, 0.f};

  int kmax = q0 + 63 - current;
  if (kmax > NS - 1) kmax = NS - 1;
  const int nkt = (kmax >= 0) ? ((kmax >> 6) + 1) : 0;
  const float inv_temp = 0.125f;  // 1/sqrt(DK)
  const int myq = q0 + wid * 16 + (lane >> 4) * 4;

  for (int kt = 0; kt < nkt; ++kt) {
    const int k0 = kt * 64;
    __syncthreads();
    // Stage full 64x64 K and V tiles: 512 bf16x8 chunks, 2 per thread.
#pragma unroll
    for (int rep = 0; rep < 2; ++rep) {
      const int c = tid + rep * 256;       // 0..511
      const int kr = c >> 3;               // key row 0..63
      const int dc = (c & 7) * 8;          // dim col 0..56
      const size_t goff = (size_t)(b * NS + k0 + kr) * ND + h * 64 + dc;
      *(bf16x8*)&Kt[kr * 72 + dc] = *(const bf16x8*)&Kg[goff];
      const bf16x8 vv = *(const bf16x8*)&V[goff];
#pragma unroll
      for (int e = 0; e < 8; ++e) Vt[(dc + e) * 72 + kr] = vv[e];
    }
    __syncthreads();

    f32x4 sf[4];
#pragma unroll
    for (int kc = 0; kc < 4; ++kc) {
      f32x4 z = {};
      const bf16x8 bk0 = *(const bf16x8*)&Kt[(kc * 16 + lr) * 72 + lk];
      const bf16x8 bk1 = *(const bf16x8*)&Kt[(kc * 16 + lr) * 72 + 32 + lk];
      z = __builtin_amdgcn_mfma_f32_16x16x32_bf16(aq0, bk0, z, 0, 0, 0);
      z = __builtin_amdgcn_mfma_f32_16x16x32_bf16(aq1, bk1, z, 0, 0, 0);
      sf[kc] = z;
    }

#pragma unroll
    for (int r = 0; r < 4; ++r) {
      float sv[4];
      float mx = -1e30f;
#pragma unroll
      for (int kc = 0; kc < 4; ++kc) {
        const int key = k0 + kc * 16 + lr;
        const bool ok = (key + current <= myq + r);
        sv[kc] = ok ? sf[kc][r] * inv_temp : -1e30f;
        mx = fmaxf(mx, sv[kc]);
      }
#pragma unroll
      for (int off = 1; off < 16; off <<= 1) mx = fmaxf(mx, __shfl_xor(mx, off, 64));
      const float mnew = fmaxf(m_run[r], mx);
      const float scale = __expf(m_run[r] - mnew);
      m_run[r] = mnew;
      l_run[r] *= scale;
#pragma unroll
      for (int j = 0; j < 4; ++j) acc[j][r] *= scale;
      float ps = 0.f;
#pragma unroll
      for (int kc = 0; kc < 4; ++kc) {
        const float pv = (sv[kc] > -1e29f) ? __expf(sv[kc] - mnew) : 0.f;
        ps += pv;
        Pw[wid][((lane >> 4) * 4 + r) * 72 + kc * 16 + lr] = (bf16)pv;
      }
#pragma unroll
      for (int off = 1; off < 16; off <<= 1) ps += __shfl_xor(ps, off, 64);
      l_run[r] += ps;
    }
    __syncthreads();

#pragma unroll
    for (int kk = 0; kk < 2; ++kk) {
      const bf16x8 ap = *(const bf16x8*)&Pw[wid][lr * 72 + kk * 32 + lk];
#pragma unroll
      for (int j = 0; j < 4; ++j) {
        const bf16x8 bv = *(const bf16x8*)&Vt[(j * 16 + lr) * 72 + kk * 32 + lk];
        acc[j] = __builtin_amdgcn_mfma_f32_16x16x32_bf16(ap, bv, acc[j], 0, 0, 0);
      }
    }
  }

#pragma unroll
  for (int j = 0; j < 4; ++j)
#pragma unroll
    for (int r = 0; r < 4; ++r) {
      const int row = myq + r;
      const float l = l_run[r];
      const float o = (l > 0.f) ? acc[j][r] / l : 0.f;
      O[(size_t)(b * NS + row) * ND + h * 64 + j * 16 + lr] = (bf16)o;
    }
}

// ---------------- host ----------------
extern "C" void kernel_launch(void* const* d_in, const int* in_sizes, int n_in,
                              void* d_out, int out_size, void* d_ws, size_t ws_size,
                              hipStream_t stream) {
  const float* x = (const float*)d_in[0];
  const float* wq = (const float*)d_in[1];
  const float* bq = (const float*)d_in[2];
  const float* wk = (const float*)d_in[3];
  const float* bk = (const float*)d_in[4];
  const float* wv = (const float*)d_in[5];
  const float* bv = (const float*)d_in[6];
  const float* wfc = (const float*)d_in[7];
  const float* bfc = (const float*)d_in[8];
  const float* ln1g = (const float*)d_in[9];
  const float* ln1b = (const float*)d_in[10];
  const float* w1f = (const float*)d_in[11];
  const float* b1f = (const float*)d_in[12];
  const float* w2f = (const float*)d_in[13];
  const float* b2f = (const float*)d_in[14];
  const float* ln2g = (const float*)d_in[15];
  const float* ln2b = (const float*)d_in[16];
  const int* cur = (const int*)d_in[17];
  float* out = (float*)d_out;

  char* ws = (char*)d_ws;
  size_t off = 0;
  auto alloc = [&](size_t bytes) {
    void* p = ws + off;
    off += (bytes + 255) & ~(size_t)255;
    return p;
  };
  bf16* xb = (bf16*)alloc((size_t)NTOK * ND * 2);   // later reused as attention output
  bf16* wqb = (bf16*)alloc((size_t)ND * ND * 2);
  bf16* wkb = (bf16*)alloc((size_t)ND * ND * 2);
  bf16* wvb = (bf16*)alloc((size_t)ND * ND * 2);
  bf16* wfcb = (bf16*)alloc((size_t)ND * ND * 2);
  bf16* w1fb = (bf16*)alloc((size_t)NDFF * ND * 2);
  bf16* w2fb = (bf16*)alloc((size_t)ND * NDFF * 2);
  bf16* Qb = (bf16*)alloc((size_t)NTOK * ND * 2);   // later reused as ln1 bf16
  bf16* Kb = (bf16*)alloc((size_t)NTOK * ND * 2);
  bf16* Vb = (bf16*)alloc((size_t)NTOK * ND * 2);
  float* z = (float*)alloc((size_t)NTOK * ND * 4);
  bf16* hb = (bf16*)alloc((size_t)NTOK * NDFF * 2);
  bf16* AO = xb;
  bf16* ln1bb = Qb;

  auto cvt = [&](const float* src, bf16* dst, int n) {
    int n4 = n >> 2;
    cvt_f32_bf16<<<dim3((n4 + 255) / 256), dim3(256), 0, stream>>>(src, dst, n4);
  };
  cvt(x, xb, NTOK * ND);
  cvt(wq, wqb, ND * ND);
  cvt(wk, wkb, ND * ND);
  cvt(wv, wvb, ND * ND);
  cvt(wfc, wfcb, ND * ND);
  cvt(w1f, w1fb, NDFF * ND);
  cvt(w2f, w2fb, ND * NDFF);

  const dim3 blk(256);
  // QKV projections
  gemm_bt<false, false, true, false><<<dim3(ND / 128, NTOK / 128), blk, 0, stream>>>(
      xb, wqb, bq, nullptr, Qb, nullptr, NTOK, ND, ND);
  gemm_bt<false, false, true, false><<<dim3(ND / 128, NTOK / 128), blk, 0, stream>>>(
      xb, wkb, bk, nullptr, Kb, nullptr, NTOK, ND, ND);
  gemm_bt<false, false, true, false><<<dim3(ND / 128, NTOK / 128), blk, 0, stream>>>(
      xb, wvb, bv, nullptr, Vb, nullptr, NTOK, ND, ND);
  // attention (writes AO = xb, safe: xb no longer needed)
  attn_k<<<dim3(NS / 64, NB * NH), blk, 0, stream>>>(Qb, Kb, Vb, AO, cur);
  // fc + residual(x) -> z (fp32)
  gemm_bt<false, true, false, true><<<dim3(ND / 128, NTOK / 128), blk, 0, stream>>>(
      AO, wfcb, bfc, x, nullptr, z, NTOK, ND, ND);
  // LN1: z -> z (fp32, in place) + ln1bb (bf16)
  layernorm_k<<<dim3(NTOK), blk, 0, stream>>>(z, ln1g, ln1b, 1e-5f, z, ln1bb);
  // FFN1 + ReLU -> hb (bf16)
  gemm_bt<true, false, true, false><<<dim3(NDFF / 128, NTOK / 128), blk, 0, stream>>>(
      ln1bb, w1fb, b1f, nullptr, hb, nullptr, NTOK, NDFF, ND);
  // FFN2 + residual(z) -> out (fp32)
  gemm_bt<false, true, false, true><<<dim3(ND / 128, NTOK / 128), blk, 0, stream>>>(
      hb, w2fb, b2f, z, nullptr, out, NTOK, ND, NDFF);
  // LN2 in place on out
  layernorm_k<<<dim3(NTOK), blk, 0, stream>>>(out, ln2g, ln2b, 1e-6f, out, nullptr);
}

// Round 3
// 378.316 us; speedup vs baseline: 1.1003x; 1.1003x over previous
//
#include <hip/hip_runtime.h>
#include <hip/hip_bf16.h>
#include <stdint.h>
#include <stddef.h>

#define NB 16
#define NS 1024
#define ND 512
#define NH 8
#define NDK 64
#define NDV 64
#define NDFF 2048
#define NTOK (NB * NS)

typedef __bf16 bf16;
typedef __attribute__((ext_vector_type(2))) __bf16 bf16x2;
typedef __attribute__((ext_vector_type(4))) __bf16 bf16x4;
typedef __attribute__((ext_vector_type(8))) __bf16 bf16x8;
typedef __attribute__((ext_vector_type(4))) float f32x4;

__device__ __forceinline__ void async_copy16(const void* g, void* l) {
  __builtin_amdgcn_global_load_lds(
      (const __attribute__((address_space(1))) void*)g,
      (__attribute__((address_space(3))) void*)l,
      16, 0, 0);
}

// ---------------- fp32 -> bf16 conversion ----------------
__global__ __launch_bounds__(256) void cvt_f32_bf16(const float* __restrict__ in,
                                                    bf16* __restrict__ out, int n4) {
  int i = blockIdx.x * 256 + threadIdx.x;
  if (i >= n4) return;
  const float4 v = ((const float4*)in)[i];
  bf16x4 o = {(bf16)v.x, (bf16)v.y, (bf16)v.z, (bf16)v.w};
  ((bf16x4*)out)[i] = o;
}

// ---------------- GEMM: C[M,N] = A[M,K] @ Bw[N,K]^T + bias (+resid) ----------------
template <bool RELU, bool RESID, bool OUTB, bool OUTF>
__global__ __launch_bounds__(256) void gemm_bt(
    const bf16* __restrict__ A, const bf16* __restrict__ Bw,
    const float* __restrict__ bias, const float* __restrict__ resid,
    bf16* __restrict__ Cb, float* __restrict__ Cf,
    int M, int N, int K) {
  __shared__ bf16 As[128 * 32];
  __shared__ bf16 Bs[128 * 32];
  const int tid = threadIdx.x;
  const int lane = tid & 63;
  const int wid = tid >> 6;
  const int tm = blockIdx.y, tn = blockIdx.x;
  const int wm = wid >> 1, wn = wid & 1;
  const int lr = lane & 15, lk = (lane >> 4) * 8;
  const int srow = lane >> 2, scol = (lane & 3) * 8;

  f32x4 acc[4][4] = {};

  const bf16* Abase = A + (size_t)(tm * 128 + srow) * K + scol;
  const bf16* Bbase = Bw + (size_t)(tn * 128 + srow) * K + scol;
  const int kiters = K >> 5;

  for (int kb = 0; kb < kiters; ++kb) {
    __syncthreads();
#pragma unroll
    for (int s2 = 0; s2 < 2; ++s2) {
      const int seg = wid * 2 + s2;
      async_copy16(Abase + (size_t)seg * 16 * K + kb * 32, &As[seg * 512]);
      async_copy16(Bbase + (size_t)seg * 16 * K + kb * 32, &Bs[seg * 512]);
    }
    __syncthreads();
    bf16x8 af[4], bfr[4];
#pragma unroll
    for (int i = 0; i < 4; ++i)
      af[i] = *(const bf16x8*)&As[(wm * 64 + i * 16 + lr) * 32 + lk];
#pragma unroll
    for (int j = 0; j < 4; ++j)
      bfr[j] = *(const bf16x8*)&Bs[(wn * 64 + j * 16 + lr) * 32 + lk];
#pragma unroll
    for (int i = 0; i < 4; ++i)
#pragma unroll
      for (int j = 0; j < 4; ++j)
        acc[i][j] = __builtin_amdgcn_mfma_f32_16x16x32_bf16(af[i], bfr[j], acc[i][j], 0, 0, 0);
  }

#pragma unroll
  for (int i = 0; i < 4; ++i) {
    const int row0 = tm * 128 + wm * 64 + i * 16 + (lane >> 4) * 4;
#pragma unroll
    for (int j = 0; j < 4; ++j) {
      const int col = tn * 128 + wn * 64 + j * 16 + lr;
      const float bcol = bias[col];
#pragma unroll
      for (int r = 0; r < 4; ++r) {
        float c = acc[i][j][r] + bcol;
        if (RESID) c += resid[(size_t)(row0 + r) * N + col];
        if (RELU) c = fmaxf(c, 0.f);
        if (OUTB) Cb[(size_t)(row0 + r) * N + col] = (bf16)c;
        if (OUTF) Cf[(size_t)(row0 + r) * N + col] = c;
      }
    }
  }
}

// ---------------- LayerNorm (one block per row of 512) ----------------
__global__ __launch_bounds__(256) void layernorm_k(
    const float* __restrict__ in, const float* __restrict__ gam,
    const float* __restrict__ bet, float eps,
    float* __restrict__ outf, bf16* __restrict__ outb) {
  const int row = blockIdx.x;
  const int t = threadIdx.x;
  const float2 v = ((const float2*)(in + (size_t)row * ND))[t];
  float s = v.x + v.y;
  float s2 = v.x * v.x + v.y * v.y;
#pragma unroll
  for (int off = 32; off > 0; off >>= 1) {
    s += __shfl_down(s, off, 64);
    s2 += __shfl_down(s2, off, 64);
  }
  __shared__ float red[8];
  const int wid = t >> 6, lane = t & 63;
  if (lane == 0) { red[wid] = s; red[4 + wid] = s2; }
  __syncthreads();
  const float a = red[0] + red[1] + red[2] + red[3];
  const float b = red[4] + red[5] + red[6] + red[7];
  const float mu = a * (1.f / ND);
  const float var = b * (1.f / ND) - mu * mu;
  const float rstd = rsqrtf(var + eps);
  const float2 g2 = ((const float2*)gam)[t];
  const float2 b2 = ((const float2*)bet)[t];
  const float o0 = (v.x - mu) * rstd * g2.x + b2.x;
  const float o1 = (v.y - mu) * rstd * g2.y + b2.y;
  if (outf) ((float2*)(outf + (size_t)row * ND))[t] = make_float2(o0, o1);
  if (outb) {
    bf16x2 ob = {(bf16)o0, (bf16)o1};
    ((bf16x2*)(outb + (size_t)row * ND))[t] = ob;
  }
}

// ---------------- Flash attention, causal with diagonal -current ----------------
// grid: (S/64, B*H); 256 threads = 4 waves, wave w handles q rows [q0+16w, +16)
// K: global_load_lds, linear [64][64] LDS, source pre-swizzled chunk^=(row&7).
// V: reg-staged transpose into Vt[dv][key], chunk ^= (dv&7)^((dv>>3)&7) swizzle.
// Double-buffered K/V; 2 raw barriers per tile; prefetch t+1 under compute of t.
__global__ __launch_bounds__(256) void attn_k(
    const bf16* __restrict__ Q, const bf16* __restrict__ Kg,
    const bf16* __restrict__ V, bf16* __restrict__ O,
    const int* __restrict__ curp) {
  const int current = *curp;
  const int b = blockIdx.y >> 3;
  const int h = blockIdx.y & 7;
  const int q0 = blockIdx.x * 64;
  const int tid = threadIdx.x, lane = tid & 63, wid = tid >> 6;
  const int lr = lane & 15, hi2 = lane >> 4, lk = hi2 * 8;

  __shared__ bf16 Kt[2][64 * 64];
  __shared__ bf16 Vt[2][64 * 64];
  __shared__ bf16 Pw[4][16 * 72];

  const size_t qoff = (size_t)(b * NS + q0 + wid * 16 + lr) * ND + h * 64 + lk;
  const bf16x8 aq0 = *(const bf16x8*)&Q[qoff];
  const bf16x8 aq1 = *(const bf16x8*)&Q[qoff + 32];

  f32x4 acc[4] = {};
  float m_run[4] = {-1e30f, -1e30f, -1e30f, -1e30f};
  float l_run[4] = {0.f, 0.f, 0.f, 0.f};

  int kmax = q0 + 63 - current;
  if (kmax > NS - 1) kmax = NS - 1;
  const int nkt = (kmax >= 0) ? ((kmax >> 6) + 1) : 0;
  const float inv_temp = 0.125f;  // 1/sqrt(DK)
  const int myq = q0 + wid * 16 + hi2 * 4;

  const size_t base_tok = (size_t)(b * NS) * ND + h * 64;
  const int kchunk = (lane & 7) ^ (lane >> 3);  // K source chunk (pre-swizzle)
  // V staging coords (2 chunks per thread)
  const int vkr0 = tid >> 3, vdc0 = (tid & 7) * 8;
  const int vkr1 = (tid + 256) >> 3, vdc1 = (tid & 7) * 8;
  bf16x8 vreg0, vreg1;

  for (int kt = 0; kt < nkt; ++kt) {
    const int buf = kt & 1;
    if (kt == 0) {
      // prologue staging of tile 0
#pragma unroll
      for (int i = 0; i < 2; ++i) {
        const int seg = wid * 2 + i;
        const int rloc = seg * 8 + (lane >> 3);
        async_copy16(&Kg[base_tok + (size_t)rloc * ND + kchunk * 8], &Kt[0][seg * 512]);
      }
      vreg0 = *(const bf16x8*)&V[base_tok + (size_t)vkr0 * ND + vdc0];
      vreg1 = *(const bf16x8*)&V[base_tok + (size_t)vkr1 * ND + vdc1];
    }
    // ---- P1: drain tile-kt loads, write Vt, prefetch tile kt+1 ----
    asm volatile("s_waitcnt vmcnt(0)" ::: "memory");
#pragma unroll
    for (int rep = 0; rep < 2; ++rep) {
      const int kr = rep ? vkr1 : vkr0;
      const int dc = rep ? vdc1 : vdc0;
      const bf16x8 vv = rep ? vreg1 : vreg0;
#pragma unroll
      for (int e = 0; e < 8; ++e) {
        const int dv = dc + e;
        const int sw = (dv ^ (dv >> 3)) & 7;
        Vt[buf][dv * 64 + ((((kr >> 3) ^ sw) & 7) << 3) + (kr & 7)] = vv[e];
      }
    }
    if (kt + 1 < nkt) {
      const int k0n = (kt + 1) * 64;
#pragma unroll
      for (int i = 0; i < 2; ++i) {
        const int seg = wid * 2 + i;
        const int rloc = seg * 8 + (lane >> 3);
        async_copy16(&Kg[base_tok + (size_t)(k0n + rloc) * ND + kchunk * 8],
                     &Kt[buf ^ 1][seg * 512]);
      }
      vreg0 = *(const bf16x8*)&V[base_tok + (size_t)(k0n + vkr0) * ND + vdc0];
      vreg1 = *(const bf16x8*)&V[base_tok + (size_t)(k0n + vkr1) * ND + vdc1];
    }
    asm volatile("s_waitcnt lgkmcnt(0)" ::: "memory");
    __builtin_amdgcn_s_barrier();
    __builtin_amdgcn_sched_barrier(0);

    // ---- P2: QK^T, softmax, PV ----
    const int k0 = kt * 64;
    const bf16* Ktb = &Kt[buf][0];
    const bf16* Vtb = &Vt[buf][0];
    f32x4 sf[4];
#pragma unroll
    for (int kc = 0; kc < 4; ++kc) {
      const int row = kc * 16 + lr;
      const int idx0 = row * 64 + ((hi2 ^ (lr & 7)) << 3);
      f32x4 z = {};
      const bf16x8 bk0 = *(const bf16x8*)&Ktb[idx0];
      const bf16x8 bk1 = *(const bf16x8*)&Ktb[idx0 ^ 32];
      z = __builtin_amdgcn_mfma_f32_16x16x32_bf16(aq0, bk0, z, 0, 0, 0);
      z = __builtin_amdgcn_mfma_f32_16x16x32_bf16(aq1, bk1, z, 0, 0, 0);
      sf[kc] = z;
    }

#pragma unroll
    for (int r = 0; r < 4; ++r) {
      float sv[4];
      float mx = -1e30f;
#pragma unroll
      for (int kc = 0; kc < 4; ++kc) {
        const int key = k0 + kc * 16 + lr;
        const bool ok = (key + current <= myq + r);
        sv[kc] = ok ? sf[kc][r] * inv_temp : -1e30f;
        mx = fmaxf(mx, sv[kc]);
      }
#pragma unroll
      for (int off = 1; off < 16; off <<= 1) mx = fmaxf(mx, __shfl_xor(mx, off, 64));
      const float mnew = fmaxf(m_run[r], mx);
      const float scale = __expf(m_run[r] - mnew);
      m_run[r] = mnew;
      l_run[r] *= scale;
#pragma unroll
      for (int j = 0; j < 4; ++j) acc[j][r] *= scale;
      float ps = 0.f;
#pragma unroll
      for (int kc = 0; kc < 4; ++kc) {
        const float pv = (sv[kc] > -1e29f) ? __expf(sv[kc] - mnew) : 0.f;
        ps += pv;
        Pw[wid][(hi2 * 4 + r) * 72 + kc * 16 + lr] = (bf16)pv;
      }
#pragma unroll
      for (int off = 1; off < 16; off <<= 1) ps += __shfl_xor(ps, off, 64);
      l_run[r] += ps;
    }

#pragma unroll
    for (int kk = 0; kk < 2; ++kk) {
      const bf16x8 ap = *(const bf16x8*)&Pw[wid][lr * 72 + kk * 32 + lk];
      const int kb3 = kk * 4 + hi2;  // key chunk index
#pragma unroll
      for (int j = 0; j < 4; ++j) {
        const int dv = j * 16 + lr;
        const int sw = (dv ^ (dv >> 3)) & 7;
        const bf16x8 bv = *(const bf16x8*)&Vtb[dv * 64 + (((kb3 ^ sw) & 7) << 3)];
        acc[j] = __builtin_amdgcn_mfma_f32_16x16x32_bf16(ap, bv, acc[j], 0, 0, 0);
      }
    }
    asm volatile("s_waitcnt lgkmcnt(0)" ::: "memory");
    __builtin_amdgcn_s_barrier();
    __builtin_amdgcn_sched_barrier(0);
  }

#pragma unroll
  for (int j = 0; j < 4; ++j)
#pragma unroll
    for (int r = 0; r < 4; ++r) {
      const int row = myq + r;
      const float l = l_run[r];
      const float o = (l > 0.f) ? acc[j][r] / l : 0.f;
      O[(size_t)(b * NS + row) * ND + h * 64 + j * 16 + lr] = (bf16)o;
    }
}

// ---------------- host ----------------
extern "C" void kernel_launch(void* const* d_in, const int* in_sizes, int n_in,
                              void* d_out, int out_size, void* d_ws, size_t ws_size,
                              hipStream_t stream) {
  const float* x = (const float*)d_in[0];
  const float* wq = (const float*)d_in[1];
  const float* bq = (const float*)d_in[2];
  const float* wk = (const float*)d_in[3];
  const float* bk = (const float*)d_in[4];
  const float* wv = (const float*)d_in[5];
  const float* bv = (const float*)d_in[6];
  const float* wfc = (const float*)d_in[7];
  const float* bfc = (const float*)d_in[8];
  const float* ln1g = (const float*)d_in[9];
  const float* ln1b = (const float*)d_in[10];
  const float* w1f = (const float*)d_in[11];
  const float* b1f = (const float*)d_in[12];
  const float* w2f = (const float*)d_in[13];
  const float* b2f = (const float*)d_in[14];
  const float* ln2g = (const float*)d_in[15];
  const float* ln2b = (const float*)d_in[16];
  const int* cur = (const int*)d_in[17];
  float* out = (float*)d_out;

  char* ws = (char*)d_ws;
  size_t off = 0;
  auto alloc = [&](size_t bytes) {
    void* p = ws + off;
    off += (bytes + 255) & ~(size_t)255;
    return p;
  };
  bf16* xb = (bf16*)alloc((size_t)NTOK * ND * 2);   // later reused as attention output
  bf16* wqb = (bf16*)alloc((size_t)ND * ND * 2);
  bf16* wkb = (bf16*)alloc((size_t)ND * ND * 2);
  bf16* wvb = (bf16*)alloc((size_t)ND * ND * 2);
  bf16* wfcb = (bf16*)alloc((size_t)ND * ND * 2);
  bf16* w1fb = (bf16*)alloc((size_t)NDFF * ND * 2);
  bf16* w2fb = (bf16*)alloc((size_t)ND * NDFF * 2);
  bf16* Qb = (bf16*)alloc((size_t)NTOK * ND * 2);   // later reused as ln1 bf16
  bf16* Kb = (bf16*)alloc((size_t)NTOK * ND * 2);
  bf16* Vb = (bf16*)alloc((size_t)NTOK * ND * 2);
  float* z = (float*)alloc((size_t)NTOK * ND * 4);
  bf16* hb = (bf16*)alloc((size_t)NTOK * NDFF * 2);
  bf16* AO = xb;
  bf16* ln1bb = Qb;

  auto cvt = [&](const float* src, bf16* dst, int n) {
    int n4 = n >> 2;
    cvt_f32_bf16<<<dim3((n4 + 255) / 256), dim3(256), 0, stream>>>(src, dst, n4);
  };
  cvt(x, xb, NTOK * ND);
  cvt(wq, wqb, ND * ND);
  cvt(wk, wkb, ND * ND);
  cvt(wv, wvb, ND * ND);
  cvt(wfc, wfcb, ND * ND);
  cvt(w1f, w1fb, NDFF * ND);
  cvt(w2f, w2fb, ND * NDFF);

  const dim3 blk(256);
  // QKV projections
  gemm_bt<false, false, true, false><<<dim3(ND / 128, NTOK / 128), blk, 0, stream>>>(
      xb, wqb, bq, nullptr, Qb, nullptr, NTOK, ND, ND);
  gemm_bt<false, false, true, false><<<dim3(ND / 128, NTOK / 128), blk, 0, stream>>>(
      xb, wkb, bk, nullptr, Kb, nullptr, NTOK, ND, ND);
  gemm_bt<false, false, true, false><<<dim3(ND / 128, NTOK / 128), blk, 0, stream>>>(
      xb, wvb, bv, nullptr, Vb, nullptr, NTOK, ND, ND);
  // attention (writes AO = xb, safe: xb no longer needed)
  attn_k<<<dim3(NS / 64, NB * NH), blk, 0, stream>>>(Qb, Kb, Vb, AO, cur);
  // fc + residual(x) -> z (fp32)
  gemm_bt<false, true, false, true><<<dim3(ND / 128, NTOK / 128), blk, 0, stream>>>(
      AO, wfcb, bfc, x, nullptr, z, NTOK, ND, ND);
  // LN1: z -> z (fp32, in place) + ln1bb (bf16)
  layernorm_k<<<dim3(NTOK), blk, 0, stream>>>(z, ln1g, ln1b, 1e-5f, z, ln1bb);
  // FFN1 + ReLU -> hb (bf16)
  gemm_bt<true, false, true, false><<<dim3(NDFF / 128, NTOK / 128), blk, 0, stream>>>(
      ln1bb, w1fb, b1f, nullptr, hb, nullptr, NTOK, NDFF, ND);
  // FFN2 + residual(z) -> out (fp32)
  gemm_bt<false, true, false, true><<<dim3(ND / 128, NTOK / 128), blk, 0, stream>>>(
      hb, w2fb, b2f, z, nullptr, out, NTOK, ND, NDFF);
  // LN2 in place on out
  layernorm_k<<<dim3(NTOK), blk, 0, stream>>>(out, ln2g, ln2b, 1e-6f, out, nullptr);
}

// Round 4
// 287.663 us; speedup vs baseline: 1.4471x; 1.3151x over previous
//
#include <hip/hip_runtime.h>
#include <hip/hip_bf16.h>
#include <stdint.h>
#include <stddef.h>

#define NB 16
#define NS 1024
#define ND 512
#define NH 8
#define NDK 64
#define NDV 64
#define NDFF 2048
#define NTOK (NB * NS)
#define LDQ (3 * ND)  // fused QKV row stride

typedef __bf16 bf16;
typedef __attribute__((ext_vector_type(2))) __bf16 bf16x2;
typedef __attribute__((ext_vector_type(4))) __bf16 bf16x4;
typedef __attribute__((ext_vector_type(8))) __bf16 bf16x8;
typedef __attribute__((ext_vector_type(4))) float f32x4;

__device__ __forceinline__ void async_copy16(const void* g, void* l) {
  __builtin_amdgcn_global_load_lds(
      (const __attribute__((address_space(1))) void*)g,
      (__attribute__((address_space(3))) void*)l,
      16, 0, 0);
}

// ---------------- fp32 -> bf16 conversion ----------------
__global__ __launch_bounds__(256) void cvt_f32_bf16(const float* __restrict__ in,
                                                    bf16* __restrict__ out, int n4) {
  int i = blockIdx.x * 256 + threadIdx.x;
  if (i >= n4) return;
  const float4 v = ((const float4*)in)[i];
  bf16x4 o = {(bf16)v.x, (bf16)v.y, (bf16)v.z, (bf16)v.w};
  ((bf16x4*)out)[i] = o;
}

// ---------------- concat 3 bias vectors (512 each) ----------------
__global__ __launch_bounds__(512) void concat3(const float* __restrict__ a,
                                               const float* __restrict__ b,
                                               const float* __restrict__ c,
                                               float* __restrict__ o) {
  const int t = threadIdx.x;
  o[t] = a[t];
  o[512 + t] = b[t];
  o[1024 + t] = c[t];
}

// ---------------- GEMM: C[M,N] = A[M,K] @ Bw[N,K]^T + bias (+resid) ----------------
template <bool RELU, bool RESID, bool OUTB, bool OUTF>
__global__ __launch_bounds__(256) void gemm_bt(
    const bf16* __restrict__ A, const bf16* __restrict__ Bw,
    const float* __restrict__ bias, const float* __restrict__ resid,
    bf16* __restrict__ Cb, float* __restrict__ Cf,
    int M, int N, int K) {
  __shared__ bf16 As[128 * 32];
  __shared__ bf16 Bs[128 * 32];
  const int tid = threadIdx.x;
  const int lane = tid & 63;
  const int wid = tid >> 6;
  const int tm = blockIdx.y, tn = blockIdx.x;
  const int wm = wid >> 1, wn = wid & 1;
  const int lr = lane & 15, lk = (lane >> 4) * 8;
  const int srow = lane >> 2, scol = (lane & 3) * 8;

  f32x4 acc[4][4] = {};

  const bf16* Abase = A + (size_t)(tm * 128 + srow) * K + scol;
  const bf16* Bbase = Bw + (size_t)(tn * 128 + srow) * K + scol;
  const int kiters = K >> 5;

  for (int kb = 0; kb < kiters; ++kb) {
    __syncthreads();
#pragma unroll
    for (int s2 = 0; s2 < 2; ++s2) {
      const int seg = wid * 2 + s2;
      async_copy16(Abase + (size_t)seg * 16 * K + kb * 32, &As[seg * 512]);
      async_copy16(Bbase + (size_t)seg * 16 * K + kb * 32, &Bs[seg * 512]);
    }
    __syncthreads();
    bf16x8 af[4], bfr[4];
#pragma unroll
    for (int i = 0; i < 4; ++i)
      af[i] = *(const bf16x8*)&As[(wm * 64 + i * 16 + lr) * 32 + lk];
#pragma unroll
    for (int j = 0; j < 4; ++j)
      bfr[j] = *(const bf16x8*)&Bs[(wn * 64 + j * 16 + lr) * 32 + lk];
#pragma unroll
    for (int i = 0; i < 4; ++i)
#pragma unroll
      for (int j = 0; j < 4; ++j)
        acc[i][j] = __builtin_amdgcn_mfma_f32_16x16x32_bf16(af[i], bfr[j], acc[i][j], 0, 0, 0);
  }

#pragma unroll
  for (int i = 0; i < 4; ++i) {
    const int row0 = tm * 128 + wm * 64 + i * 16 + (lane >> 4) * 4;
#pragma unroll
    for (int j = 0; j < 4; ++j) {
      const int col = tn * 128 + wn * 64 + j * 16 + lr;
      const float bcol = bias[col];
#pragma unroll
      for (int r = 0; r < 4; ++r) {
        float c = acc[i][j][r] + bcol;
        if (RESID) c += resid[(size_t)(row0 + r) * N + col];
        if (RELU) c = fmaxf(c, 0.f);
        if (OUTB) Cb[(size_t)(row0 + r) * N + col] = (bf16)c;
        if (OUTF) Cf[(size_t)(row0 + r) * N + col] = c;
      }
    }
  }
}

// ---------------- LayerNorm: one wave per row of 512 ----------------
__global__ __launch_bounds__(256) void layernorm_k(
    const float* __restrict__ in, const float* __restrict__ gam,
    const float* __restrict__ bet, float eps,
    float* __restrict__ outf, bf16* __restrict__ outb) {
  const int row = blockIdx.x * 4 + (threadIdx.x >> 6);
  const int lane = threadIdx.x & 63;
  const float* rp = in + (size_t)row * ND;
  const float4 v0 = ((const float4*)rp)[lane];
  const float4 v1 = ((const float4*)rp)[lane + 64];
  float s = v0.x + v0.y + v0.z + v0.w + v1.x + v1.y + v1.z + v1.w;
  float s2 = v0.x * v0.x + v0.y * v0.y + v0.z * v0.z + v0.w * v0.w +
             v1.x * v1.x + v1.y * v1.y + v1.z * v1.z + v1.w * v1.w;
#pragma unroll
  for (int off = 1; off < 64; off <<= 1) {
    s += __shfl_xor(s, off, 64);
    s2 += __shfl_xor(s2, off, 64);
  }
  const float mu = s * (1.f / ND);
  const float var = s2 * (1.f / ND) - mu * mu;
  const float rstd = rsqrtf(var + eps);
  const float4 g0 = ((const float4*)gam)[lane];
  const float4 g1 = ((const float4*)gam)[lane + 64];
  const float4 b0 = ((const float4*)bet)[lane];
  const float4 b1 = ((const float4*)bet)[lane + 64];
  float4 o0, o1;
  o0.x = (v0.x - mu) * rstd * g0.x + b0.x;
  o0.y = (v0.y - mu) * rstd * g0.y + b0.y;
  o0.z = (v0.z - mu) * rstd * g0.z + b0.z;
  o0.w = (v0.w - mu) * rstd * g0.w + b0.w;
  o1.x = (v1.x - mu) * rstd * g1.x + b1.x;
  o1.y = (v1.y - mu) * rstd * g1.y + b1.y;
  o1.z = (v1.z - mu) * rstd * g1.z + b1.z;
  o1.w = (v1.w - mu) * rstd * g1.w + b1.w;
  if (outf) {
    float* op = outf + (size_t)row * ND;
    ((float4*)op)[lane] = o0;
    ((float4*)op)[lane + 64] = o1;
  }
  if (outb) {
    bf16* op = outb + (size_t)row * ND;
    bf16x4 ob0 = {(bf16)o0.x, (bf16)o0.y, (bf16)o0.z, (bf16)o0.w};
    bf16x4 ob1 = {(bf16)o1.x, (bf16)o1.y, (bf16)o1.z, (bf16)o1.w};
    ((bf16x4*)op)[lane] = ob0;
    ((bf16x4*)op)[lane + 64] = ob1;
  }
}

// ---------------- Flash attention, causal diag -current, swapped-operand ----------------
// grid: (B*H, S/64); 256 threads = 4 waves, wave w owns q rows [q0+16w, +16).
// Swapped QK^T: S[key][q] -> per-lane row stats (q = lane&15), 4 shuffles/tile.
// Swapped PV: acc = O[dv][q] -> per-lane rescale, vectorized epilogue store.
__global__ __launch_bounds__(256) void attn_k(
    const bf16* __restrict__ QKV, bf16* __restrict__ O,
    const int* __restrict__ curp) {
  const int current = *curp;
  const int bh = blockIdx.x;
  const int b = bh >> 3, h = bh & 7;
  const int q0 = blockIdx.y * 64;
  const int tid = threadIdx.x, lane = tid & 63, wid = tid >> 6;
  const int lr = lane & 15, hi2 = lane >> 4, lk = hi2 * 8;

  __shared__ bf16 Kt[2][64 * 64];
  __shared__ bf16 Vt[64 * 64];
  __shared__ bf16 Pw[4][16 * 72];

  const bf16* Qg = QKV;
  const bf16* Kg = QKV + ND;
  const bf16* Vg = QKV + 2 * ND;

  const size_t qoff = (size_t)(b * NS + q0 + wid * 16 + lr) * LDQ + h * 64 + lk;
  const bf16x8 aq0 = *(const bf16x8*)&Qg[qoff];
  const bf16x8 aq1 = *(const bf16x8*)&Qg[qoff + 32];

  f32x4 acc[4] = {};
  float m_run = -1e30f, l_run = 0.f;  // per q-row (q = q0 + wid*16 + lr)

  int kmax = q0 + 63 - current;
  if (kmax > NS - 1) kmax = NS - 1;
  const int nkt = (kmax >= 0) ? ((kmax >> 6) + 1) : 0;
  const float inv_temp = 0.125f;  // 1/sqrt(DK)
  const int qv = q0 + wid * 16 + lr;

  const size_t base_tok = (size_t)(b * NS) * LDQ + h * 64;
  const int kchunk = (lane & 7) ^ (lane >> 3);  // K source pre-swizzle
  const int vkr0 = tid >> 3, vdc = (tid & 7) * 8;
  const int vkr1 = vkr0 + 32;
  bf16x8 vreg0, vreg1;

  for (int kt = 0; kt < nkt; ++kt) {
    const int buf = kt & 1;
    if (kt == 0) {
#pragma unroll
      for (int i = 0; i < 2; ++i) {
        const int seg = wid * 2 + i;
        const int rloc = seg * 8 + (lane >> 3);
        async_copy16(&Kg[base_tok + (size_t)rloc * LDQ + kchunk * 8], &Kt[0][seg * 512]);
      }
      vreg0 = *(const bf16x8*)&Vg[base_tok + (size_t)vkr0 * LDQ + vdc];
      vreg1 = *(const bf16x8*)&Vg[base_tok + (size_t)vkr1 * LDQ + vdc];
    }
    // ---- P1: drain tile-kt loads, write Vt, prefetch kt+1 ----
    asm volatile("s_waitcnt vmcnt(0)" ::: "memory");
#pragma unroll
    for (int rep = 0; rep < 2; ++rep) {
      const int kr = rep ? vkr1 : vkr0;
      const bf16x8 vv = rep ? vreg1 : vreg0;
#pragma unroll
      for (int e = 0; e < 8; ++e) {
        const int dv = vdc + e;
        const int sw = (dv ^ (dv >> 3)) & 7;
        Vt[dv * 64 + ((((kr >> 3) ^ sw) & 7) << 3) + (kr & 7)] = vv[e];
      }
    }
    if (kt + 1 < nkt) {
      const int k0n = (kt + 1) * 64;
#pragma unroll
      for (int i = 0; i < 2; ++i) {
        const int seg = wid * 2 + i;
        const int rloc = seg * 8 + (lane >> 3);
        async_copy16(&Kg[base_tok + (size_t)(k0n + rloc) * LDQ + kchunk * 8],
                     &Kt[buf ^ 1][seg * 512]);
      }
      vreg0 = *(const bf16x8*)&Vg[base_tok + (size_t)(k0n + vkr0) * LDQ + vdc];
      vreg1 = *(const bf16x8*)&Vg[base_tok + (size_t)(k0n + vkr1) * LDQ + vdc];
    }
    asm volatile("s_waitcnt lgkmcnt(0)" ::: "memory");
    __builtin_amdgcn_s_barrier();
    __builtin_amdgcn_sched_barrier(0);

    // ---- P2: QK^T (swapped), softmax, PV (swapped) ----
    const int k0 = kt * 64;
    const bf16* Ktb = &Kt[buf][0];
    f32x4 sf[4];
    __builtin_amdgcn_s_setprio(1);
#pragma unroll
    for (int kc = 0; kc < 4; ++kc) {
      const int row = kc * 16 + lr;
      const int idx0 = row * 64 + ((hi2 ^ (lr & 7)) << 3);
      f32x4 z = {};
      const bf16x8 bk0 = *(const bf16x8*)&Ktb[idx0];
      const bf16x8 bk1 = *(const bf16x8*)&Ktb[idx0 ^ 32];
      z = __builtin_amdgcn_mfma_f32_16x16x32_bf16(bk0, aq0, z, 0, 0, 0);  // A=K, B=Q
      z = __builtin_amdgcn_mfma_f32_16x16x32_bf16(bk1, aq1, z, 0, 0, 0);
      sf[kc] = z;  // S[key = k0+kc*16+hi2*4+r][q = qv]
    }
    __builtin_amdgcn_s_setprio(0);

    float sv[16];
    float mx = -1e30f;
    const int keyb = k0 + hi2 * 4;
#pragma unroll
    for (int kc = 0; kc < 4; ++kc)
#pragma unroll
      for (int r = 0; r < 4; ++r) {
        const int key = keyb + kc * 16 + r;
        const float s = (key + current <= qv) ? sf[kc][r] * inv_temp : -1e30f;
        sv[kc * 4 + r] = s;
        mx = fmaxf(mx, s);
      }
    mx = fmaxf(mx, __shfl_xor(mx, 16, 64));
    mx = fmaxf(mx, __shfl_xor(mx, 32, 64));
    const float mnew = fmaxf(m_run, mx);
    const float scale = __expf(m_run - mnew);
    m_run = mnew;
    float ps = 0.f;
    bf16x4 pb[4];
#pragma unroll
    for (int kc = 0; kc < 4; ++kc)
#pragma unroll
      for (int r = 0; r < 4; ++r) {
        const float p = (sv[kc * 4 + r] > -1e29f) ? __expf(sv[kc * 4 + r] - mnew) : 0.f;
        ps += p;
        pb[kc][r] = (bf16)p;
      }
    ps += __shfl_xor(ps, 16, 64);
    ps += __shfl_xor(ps, 32, 64);
    l_run = l_run * scale + ps;
#pragma unroll
    for (int j = 0; j < 4; ++j)
#pragma unroll
      for (int r = 0; r < 4; ++r) acc[j][r] *= scale;
#pragma unroll
    for (int kc = 0; kc < 4; ++kc)
      *(bf16x4*)&Pw[wid][lr * 72 + kc * 16 + hi2 * 4] = pb[kc];

    __builtin_amdgcn_s_setprio(1);
#pragma unroll
    for (int kk = 0; kk < 2; ++kk) {
      const bf16x8 ap = *(const bf16x8*)&Pw[wid][lr * 72 + kk * 32 + lk];
#pragma unroll
      for (int j = 0; j < 4; ++j) {
        const int dv = j * 16 + lr;
        const int sw = (dv ^ (dv >> 3)) & 7;
        const bf16x8 bv = *(const bf16x8*)&Vt[dv * 64 + ((((kk * 4 + hi2) ^ sw) & 7) << 3)];
        acc[j] = __builtin_amdgcn_mfma_f32_16x16x32_bf16(bv, ap, acc[j], 0, 0, 0);  // A=V^T, B=P
      }
    }
    __builtin_amdgcn_s_setprio(0);
    asm volatile("s_waitcnt lgkmcnt(0)" ::: "memory");
    __builtin_amdgcn_s_barrier();
    __builtin_amdgcn_sched_barrier(0);
  }

  // epilogue: acc[j][r] = O[dv = j*16 + hi2*4 + r][q = qv]
  const float linv = (l_run > 0.f) ? 1.f / l_run : 0.f;
#pragma unroll
  for (int j = 0; j < 4; ++j) {
    bf16x4 ov;
#pragma unroll
    for (int r = 0; r < 4; ++r) ov[r] = (bf16)(acc[j][r] * linv);
    *(bf16x4*)&O[(size_t)(b * NS + qv) * ND + h * 64 + j * 16 + hi2 * 4] = ov;
  }
}

// ---------------- host ----------------
extern "C" void kernel_launch(void* const* d_in, const int* in_sizes, int n_in,
                              void* d_out, int out_size, void* d_ws, size_t ws_size,
                              hipStream_t stream) {
  const float* x = (const float*)d_in[0];
  const float* wq = (const float*)d_in[1];
  const float* bq = (const float*)d_in[2];
  const float* wk = (const float*)d_in[3];
  const float* bk = (const float*)d_in[4];
  const float* wv = (const float*)d_in[5];
  const float* bv = (const float*)d_in[6];
  const float* wfc = (const float*)d_in[7];
  const float* bfc = (const float*)d_in[8];
  const float* ln1g = (const float*)d_in[9];
  const float* ln1b = (const float*)d_in[10];
  const float* w1f = (const float*)d_in[11];
  const float* b1f = (const float*)d_in[12];
  const float* w2f = (const float*)d_in[13];
  const float* b2f = (const float*)d_in[14];
  const float* ln2g = (const float*)d_in[15];
  const float* ln2b = (const float*)d_in[16];
  const int* cur = (const int*)d_in[17];
  float* out = (float*)d_out;

  char* ws = (char*)d_ws;
  size_t off = 0;
  auto alloc = [&](size_t bytes) {
    void* p = ws + off;
    off += (bytes + 255) & ~(size_t)255;
    return p;
  };
  bf16* xb = (bf16*)alloc((size_t)NTOK * ND * 2);     // reused as attention output
  bf16* w3b = (bf16*)alloc((size_t)3 * ND * ND * 2);  // [wq;wk;wv] fused
  bf16* wfcb = (bf16*)alloc((size_t)ND * ND * 2);
  bf16* w1fb = (bf16*)alloc((size_t)NDFF * ND * 2);
  bf16* w2fb = (bf16*)alloc((size_t)ND * NDFF * 2);
  float* b3 = (float*)alloc((size_t)3 * ND * 4);
  bf16* qkvb = (bf16*)alloc((size_t)NTOK * LDQ * 2);  // reused as ln1 bf16
  float* z = (float*)alloc((size_t)NTOK * ND * 4);
  bf16* hb = (bf16*)alloc((size_t)NTOK * NDFF * 2);
  bf16* AO = xb;
  bf16* ln1bb = qkvb;

  auto cvt = [&](const float* src, bf16* dst, int n) {
    int n4 = n >> 2;
    cvt_f32_bf16<<<dim3((n4 + 255) / 256), dim3(256), 0, stream>>>(src, dst, n4);
  };
  cvt(x, xb, NTOK * ND);
  cvt(wq, w3b, ND * ND);
  cvt(wk, w3b + ND * ND, ND * ND);
  cvt(wv, w3b + 2 * ND * ND, ND * ND);
  cvt(wfc, wfcb, ND * ND);
  cvt(w1f, w1fb, NDFF * ND);
  cvt(w2f, w2fb, ND * NDFF);
  concat3<<<dim3(1), dim3(512), 0, stream>>>(bq, bk, bv, b3);

  const dim3 blk(256);
  // fused QKV projection: [16384,1536] = x @ W3^T
  gemm_bt<false, false, true, false><<<dim3(LDQ / 128, NTOK / 128), blk, 0, stream>>>(
      xb, w3b, b3, nullptr, qkvb, nullptr, NTOK, LDQ, ND);
  // attention (writes AO = xb)
  attn_k<<<dim3(NB * NH, NS / 64), blk, 0, stream>>>(qkvb, AO, cur);
  // fc + residual(x) -> z (fp32)
  gemm_bt<false, true, false, true><<<dim3(ND / 128, NTOK / 128), blk, 0, stream>>>(
      AO, wfcb, bfc, x, nullptr, z, NTOK, ND, ND);
  // LN1: z -> z (fp32) + ln1bb (bf16)
  layernorm_k<<<dim3(NTOK / 4), blk, 0, stream>>>(z, ln1g, ln1b, 1e-5f, z, ln1bb);
  // FFN1 + ReLU -> hb (bf16)
  gemm_bt<true, false, true, false><<<dim3(NDFF / 128, NTOK / 128), blk, 0, stream>>>(
      ln1bb, w1fb, b1f, nullptr, hb, nullptr, NTOK, NDFF, ND);
  // FFN2 + residual(z) -> out (fp32)
  gemm_bt<false, true, false, true><<<dim3(ND / 128, NTOK / 128), blk, 0, stream>>>(
      hb, w2fb, b2f, z, nullptr, out, NTOK, ND, NDFF);
  // LN2 in place on out
  layernorm_k<<<dim3(NTOK / 4), blk, 0, stream>>>(out, ln2g, ln2b, 1e-6f, out, nullptr);
}

// Round 5
// 262.228 us; speedup vs baseline: 1.5875x; 1.0970x over previous
//
#include <hip/hip_runtime.h>
#include <hip/hip_bf16.h>
#include <stdint.h>
#include <stddef.h>

#define NB 16
#define NS 1024
#define ND 512
#define NH 8
#define NDK 64
#define NDV 64
#define NDFF 2048
#define NTOK (NB * NS)
#define LDQ (3 * ND)  // fused QKV row stride

typedef __bf16 bf16;
typedef __attribute__((ext_vector_type(2))) __bf16 bf16x2;
typedef __attribute__((ext_vector_type(4))) __bf16 bf16x4;
typedef __attribute__((ext_vector_type(8))) __bf16 bf16x8;
typedef __attribute__((ext_vector_type(4))) float f32x4;

__device__ __forceinline__ void async_copy16(const void* g, void* l) {
  __builtin_amdgcn_global_load_lds(
      (const __attribute__((address_space(1))) void*)g,
      (__attribute__((address_space(3))) void*)l,
      16, 0, 0);
}

// ---------------- fp32 -> bf16 conversion ----------------
__global__ __launch_bounds__(256) void cvt_f32_bf16(const float* __restrict__ in,
                                                    bf16* __restrict__ out, int n4) {
  int i = blockIdx.x * 256 + threadIdx.x;
  if (i >= n4) return;
  const float4 v = ((const float4*)in)[i];
  bf16x4 o = {(bf16)v.x, (bf16)v.y, (bf16)v.z, (bf16)v.w};
  ((bf16x4*)out)[i] = o;
}

// ---------------- concat 3 bias vectors (512 each) ----------------
__global__ __launch_bounds__(512) void concat3(const float* __restrict__ a,
                                               const float* __restrict__ b,
                                               const float* __restrict__ c,
                                               float* __restrict__ o) {
  const int t = threadIdx.x;
  o[t] = a[t];
  o[512 + t] = b[t];
  o[1024 + t] = c[t];
}

// ---------------- GEMM: C[M,N] = A[M,K] @ Bw[N,K]^T + bias (+resid) ----------------
// 128x128 tile, BK=32, 256 threads (4 waves 2x2), mfma_f32_16x16x32_bf16.
// 2-phase pipelined: double-buffered LDS, stage(t+1) issued before compute(t),
// one vmcnt(0)+s_barrier per K-step. XCD-swizzled block ids (grids are %8==0).
template <bool RELU, bool RESID, bool OUTB, bool OUTF>
__global__ __launch_bounds__(256) void gemm_bt(
    const bf16* __restrict__ A, const bf16* __restrict__ Bw,
    const float* __restrict__ bias, const float* __restrict__ resid,
    bf16* __restrict__ Cb, float* __restrict__ Cf,
    int M, int N, int K) {
  __shared__ bf16 As[2][128 * 32];
  __shared__ bf16 Bs[2][128 * 32];
  const int tid = threadIdx.x;
  const int lane = tid & 63;
  const int wid = tid >> 6;

  // bijective XCD swizzle: consecutive virtual ids (sharing an A-panel) on one XCD
  const int nwg = gridDim.x * gridDim.y;
  int id = blockIdx.y * gridDim.x + blockIdx.x;
  id = (id & 7) * (nwg >> 3) + (id >> 3);
  const int tn = id % gridDim.x, tm = id / gridDim.x;

  const int wm = wid >> 1, wn = wid & 1;
  const int lr = lane & 15, lk = (lane >> 4) * 8;
  const int srow = lane >> 2, scol = (lane & 3) * 8;

  f32x4 acc[4][4] = {};

  const bf16* Abase = A + (size_t)(tm * 128 + srow) * K + scol;
  const bf16* Bbase = Bw + (size_t)(tn * 128 + srow) * K + scol;
  const int kiters = K >> 5;

  auto stage = [&](int buf, int kb) {
#pragma unroll
    for (int s2 = 0; s2 < 2; ++s2) {
      const int seg = wid * 2 + s2;
      async_copy16(Abase + (size_t)seg * 16 * K + kb * 32, &As[buf][seg * 512]);
      async_copy16(Bbase + (size_t)seg * 16 * K + kb * 32, &Bs[buf][seg * 512]);
    }
  };

  stage(0, 0);
  asm volatile("s_waitcnt vmcnt(0)" ::: "memory");
  __builtin_amdgcn_s_barrier();
  __builtin_amdgcn_sched_barrier(0);

  int buf = 0;
  for (int kb = 0; kb < kiters; ++kb) {
    if (kb + 1 < kiters) stage(buf ^ 1, kb + 1);
    bf16x8 af[4], bfr[4];
#pragma unroll
    for (int i = 0; i < 4; ++i)
      af[i] = *(const bf16x8*)&As[buf][(wm * 64 + i * 16 + lr) * 32 + lk];
#pragma unroll
    for (int j = 0; j < 4; ++j)
      bfr[j] = *(const bf16x8*)&Bs[buf][(wn * 64 + j * 16 + lr) * 32 + lk];
#pragma unroll
    for (int i = 0; i < 4; ++i)
#pragma unroll
      for (int j = 0; j < 4; ++j)
        acc[i][j] = __builtin_amdgcn_mfma_f32_16x16x32_bf16(af[i], bfr[j], acc[i][j], 0, 0, 0);
    asm volatile("s_waitcnt vmcnt(0)" ::: "memory");
    __builtin_amdgcn_s_barrier();
    __builtin_amdgcn_sched_barrier(0);
    buf ^= 1;
  }

#pragma unroll
  for (int i = 0; i < 4; ++i) {
    const int row0 = tm * 128 + wm * 64 + i * 16 + (lane >> 4) * 4;
#pragma unroll
    for (int j = 0; j < 4; ++j) {
      const int col = tn * 128 + wn * 64 + j * 16 + lr;
      const float bcol = bias[col];
#pragma unroll
      for (int r = 0; r < 4; ++r) {
        float c = acc[i][j][r] + bcol;
        if (RESID) c += resid[(size_t)(row0 + r) * N + col];
        if (RELU) c = fmaxf(c, 0.f);
        if (OUTB) Cb[(size_t)(row0 + r) * N + col] = (bf16)c;
        if (OUTF) Cf[(size_t)(row0 + r) * N + col] = c;
      }
    }
  }
}

// ---------------- LayerNorm: one wave per row of 512 ----------------
__global__ __launch_bounds__(256) void layernorm_k(
    const float* __restrict__ in, const float* __restrict__ gam,
    const float* __restrict__ bet, float eps,
    float* __restrict__ outf, bf16* __restrict__ outb) {
  const int row = blockIdx.x * 4 + (threadIdx.x >> 6);
  const int lane = threadIdx.x & 63;
  const float* rp = in + (size_t)row * ND;
  const float4 v0 = ((const float4*)rp)[lane];
  const float4 v1 = ((const float4*)rp)[lane + 64];
  float s = v0.x + v0.y + v0.z + v0.w + v1.x + v1.y + v1.z + v1.w;
  float s2 = v0.x * v0.x + v0.y * v0.y + v0.z * v0.z + v0.w * v0.w +
             v1.x * v1.x + v1.y * v1.y + v1.z * v1.z + v1.w * v1.w;
#pragma unroll
  for (int off = 1; off < 64; off <<= 1) {
    s += __shfl_xor(s, off, 64);
    s2 += __shfl_xor(s2, off, 64);
  }
  const float mu = s * (1.f / ND);
  const float var = s2 * (1.f / ND) - mu * mu;
  const float rstd = rsqrtf(var + eps);
  const float4 g0 = ((const float4*)gam)[lane];
  const float4 g1 = ((const float4*)gam)[lane + 64];
  const float4 b0 = ((const float4*)bet)[lane];
  const float4 b1 = ((const float4*)bet)[lane + 64];
  float4 o0, o1;
  o0.x = (v0.x - mu) * rstd * g0.x + b0.x;
  o0.y = (v0.y - mu) * rstd * g0.y + b0.y;
  o0.z = (v0.z - mu) * rstd * g0.z + b0.z;
  o0.w = (v0.w - mu) * rstd * g0.w + b0.w;
  o1.x = (v1.x - mu) * rstd * g1.x + b1.x;
  o1.y = (v1.y - mu) * rstd * g1.y + b1.y;
  o1.z = (v1.z - mu) * rstd * g1.z + b1.z;
  o1.w = (v1.w - mu) * rstd * g1.w + b1.w;
  if (outf) {
    float* op = outf + (size_t)row * ND;
    ((float4*)op)[lane] = o0;
    ((float4*)op)[lane + 64] = o1;
  }
  if (outb) {
    bf16* op = outb + (size_t)row * ND;
    bf16x4 ob0 = {(bf16)o0.x, (bf16)o0.y, (bf16)o0.z, (bf16)o0.w};
    bf16x4 ob1 = {(bf16)o1.x, (bf16)o1.y, (bf16)o1.z, (bf16)o1.w};
    ((bf16x4*)op)[lane] = ob0;
    ((bf16x4*)op)[lane + 64] = ob1;
  }
}

// ---------------- Flash attention, causal diag -current, swapped-operand ----------------
__global__ __launch_bounds__(256) void attn_k(
    const bf16* __restrict__ QKV, bf16* __restrict__ O,
    const int* __restrict__ curp) {
  const int current = *curp;
  const int bh = blockIdx.x;
  const int b = bh >> 3, h = bh & 7;
  const int q0 = blockIdx.y * 64;
  const int tid = threadIdx.x, lane = tid & 63, wid = tid >> 6;
  const int lr = lane & 15, hi2 = lane >> 4, lk = hi2 * 8;

  __shared__ bf16 Kt[2][64 * 64];
  __shared__ bf16 Vt[64 * 64];
  __shared__ bf16 Pw[4][16 * 72];

  const bf16* Qg = QKV;
  const bf16* Kg = QKV + ND;
  const bf16* Vg = QKV + 2 * ND;

  const size_t qoff = (size_t)(b * NS + q0 + wid * 16 + lr) * LDQ + h * 64 + lk;
  const bf16x8 aq0 = *(const bf16x8*)&Qg[qoff];
  const bf16x8 aq1 = *(const bf16x8*)&Qg[qoff + 32];

  f32x4 acc[4] = {};
  float m_run = -1e30f, l_run = 0.f;

  int kmax = q0 + 63 - current;
  if (kmax > NS - 1) kmax = NS - 1;
  const int nkt = (kmax >= 0) ? ((kmax >> 6) + 1) : 0;
  const float inv_temp = 0.125f;
  const int qv = q0 + wid * 16 + lr;

  const size_t base_tok = (size_t)(b * NS) * LDQ + h * 64;
  const int kchunk = (lane & 7) ^ (lane >> 3);
  const int vkr0 = tid >> 3, vdc = (tid & 7) * 8;
  const int vkr1 = vkr0 + 32;
  bf16x8 vreg0, vreg1;

  for (int kt = 0; kt < nkt; ++kt) {
    const int buf = kt & 1;
    if (kt == 0) {
#pragma unroll
      for (int i = 0; i < 2; ++i) {
        const int seg = wid * 2 + i;
        const int rloc = seg * 8 + (lane >> 3);
        async_copy16(&Kg[base_tok + (size_t)rloc * LDQ + kchunk * 8], &Kt[0][seg * 512]);
      }
      vreg0 = *(const bf16x8*)&Vg[base_tok + (size_t)vkr0 * LDQ + vdc];
      vreg1 = *(const bf16x8*)&Vg[base_tok + (size_t)vkr1 * LDQ + vdc];
    }
    asm volatile("s_waitcnt vmcnt(0)" ::: "memory");
#pragma unroll
    for (int rep = 0; rep < 2; ++rep) {
      const int kr = rep ? vkr1 : vkr0;
      const bf16x8 vv = rep ? vreg1 : vreg0;
#pragma unroll
      for (int e = 0; e < 8; ++e) {
        const int dv = vdc + e;
        const int sw = (dv ^ (dv >> 3)) & 7;
        Vt[dv * 64 + ((((kr >> 3) ^ sw) & 7) << 3) + (kr & 7)] = vv[e];
      }
    }
    if (kt + 1 < nkt) {
      const int k0n = (kt + 1) * 64;
#pragma unroll
      for (int i = 0; i < 2; ++i) {
        const int seg = wid * 2 + i;
        const int rloc = seg * 8 + (lane >> 3);
        async_copy16(&Kg[base_tok + (size_t)(k0n + rloc) * LDQ + kchunk * 8],
                     &Kt[buf ^ 1][seg * 512]);
      }
      vreg0 = *(const bf16x8*)&Vg[base_tok + (size_t)(k0n + vkr0) * LDQ + vdc];
      vreg1 = *(const bf16x8*)&Vg[base_tok + (size_t)(k0n + vkr1) * LDQ + vdc];
    }
    asm volatile("s_waitcnt lgkmcnt(0)" ::: "memory");
    __builtin_amdgcn_s_barrier();
    __builtin_amdgcn_sched_barrier(0);

    const int k0 = kt * 64;
    const bf16* Ktb = &Kt[buf][0];
    f32x4 sf[4];
    __builtin_amdgcn_s_setprio(1);
#pragma unroll
    for (int kc = 0; kc < 4; ++kc) {
      const int row = kc * 16 + lr;
      const int idx0 = row * 64 + ((hi2 ^ (lr & 7)) << 3);
      f32x4 z = {};
      const bf16x8 bk0 = *(const bf16x8*)&Ktb[idx0];
      const bf16x8 bk1 = *(const bf16x8*)&Ktb[idx0 ^ 32];
      z = __builtin_amdgcn_mfma_f32_16x16x32_bf16(bk0, aq0, z, 0, 0, 0);
      z = __builtin_amdgcn_mfma_f32_16x16x32_bf16(bk1, aq1, z, 0, 0, 0);
      sf[kc] = z;
    }
    __builtin_amdgcn_s_setprio(0);

    float sv[16];
    float mx = -1e30f;
    const int keyb = k0 + hi2 * 4;
#pragma unroll
    for (int kc = 0; kc < 4; ++kc)
#pragma unroll
      for (int r = 0; r < 4; ++r) {
        const int key = keyb + kc * 16 + r;
        const float s = (key + current <= qv) ? sf[kc][r] * inv_temp : -1e30f;
        sv[kc * 4 + r] = s;
        mx = fmaxf(mx, s);
      }
    mx = fmaxf(mx, __shfl_xor(mx, 16, 64));
    mx = fmaxf(mx, __shfl_xor(mx, 32, 64));
    const float mnew = fmaxf(m_run, mx);
    const float scale = __expf(m_run - mnew);
    m_run = mnew;
    float ps = 0.f;
    bf16x4 pb[4];
#pragma unroll
    for (int kc = 0; kc < 4; ++kc)
#pragma unroll
      for (int r = 0; r < 4; ++r) {
        const float p = (sv[kc * 4 + r] > -1e29f) ? __expf(sv[kc * 4 + r] - mnew) : 0.f;
        ps += p;
        pb[kc][r] = (bf16)p;
      }
    ps += __shfl_xor(ps, 16, 64);
    ps += __shfl_xor(ps, 32, 64);
    l_run = l_run * scale + ps;
#pragma unroll
    for (int j = 0; j < 4; ++j)
#pragma unroll
      for (int r = 0; r < 4; ++r) acc[j][r] *= scale;
#pragma unroll
    for (int kc = 0; kc < 4; ++kc)
      *(bf16x4*)&Pw[wid][lr * 72 + kc * 16 + hi2 * 4] = pb[kc];

    __builtin_amdgcn_s_setprio(1);
#pragma unroll
    for (int kk = 0; kk < 2; ++kk) {
      const bf16x8 ap = *(const bf16x8*)&Pw[wid][lr * 72 + kk * 32 + lk];
#pragma unroll
      for (int j = 0; j < 4; ++j) {
        const int dv = j * 16 + lr;
        const int sw = (dv ^ (dv >> 3)) & 7;
        const bf16x8 bv = *(const bf16x8*)&Vt[dv * 64 + ((((kk * 4 + hi2) ^ sw) & 7) << 3)];
        acc[j] = __builtin_amdgcn_mfma_f32_16x16x32_bf16(bv, ap, acc[j], 0, 0, 0);
      }
    }
    __builtin_amdgcn_s_setprio(0);
    asm volatile("s_waitcnt lgkmcnt(0)" ::: "memory");
    __builtin_amdgcn_s_barrier();
    __builtin_amdgcn_sched_barrier(0);
  }

  const float linv = (l_run > 0.f) ? 1.f / l_run : 0.f;
#pragma unroll
  for (int j = 0; j < 4; ++j) {
    bf16x4 ov;
#pragma unroll
    for (int r = 0; r < 4; ++r) ov[r] = (bf16)(acc[j][r] * linv);
    *(bf16x4*)&O[(size_t)(b * NS + qv) * ND + h * 64 + j * 16 + hi2 * 4] = ov;
  }
}

// ---------------- host ----------------
extern "C" void kernel_launch(void* const* d_in, const int* in_sizes, int n_in,
                              void* d_out, int out_size, void* d_ws, size_t ws_size,
                              hipStream_t stream) {
  const float* x = (const float*)d_in[0];
  const float* wq = (const float*)d_in[1];
  const float* bq = (const float*)d_in[2];
  const float* wk = (const float*)d_in[3];
  const float* bk = (const float*)d_in[4];
  const float* wv = (const float*)d_in[5];
  const float* bv = (const float*)d_in[6];
  const float* wfc = (const float*)d_in[7];
  const float* bfc = (const float*)d_in[8];
  const float* ln1g = (const float*)d_in[9];
  const float* ln1b = (const float*)d_in[10];
  const float* w1f = (const float*)d_in[11];
  const float* b1f = (const float*)d_in[12];
  const float* w2f = (const float*)d_in[13];
  const float* b2f = (const float*)d_in[14];
  const float* ln2g = (const float*)d_in[15];
  const float* ln2b = (const float*)d_in[16];
  const int* cur = (const int*)d_in[17];
  float* out = (float*)d_out;

  char* ws = (char*)d_ws;
  size_t off = 0;
  auto alloc = [&](size_t bytes) {
    void* p = ws + off;
    off += (bytes + 255) & ~(size_t)255;
    return p;
  };
  bf16* xb = (bf16*)alloc((size_t)NTOK * ND * 2);     // reused as attention output
  bf16* w3b = (bf16*)alloc((size_t)3 * ND * ND * 2);  // [wq;wk;wv] fused
  bf16* wfcb = (bf16*)alloc((size_t)ND * ND * 2);
  bf16* w1fb = (bf16*)alloc((size_t)NDFF * ND * 2);
  bf16* w2fb = (bf16*)alloc((size_t)ND * NDFF * 2);
  float* b3 = (float*)alloc((size_t)3 * ND * 4);
  bf16* qkvb = (bf16*)alloc((size_t)NTOK * LDQ * 2);  // reused as ln1 bf16
  float* z = (float*)alloc((size_t)NTOK * ND * 4);
  bf16* hb = (bf16*)alloc((size_t)NTOK * NDFF * 2);
  bf16* AO = xb;
  bf16* ln1bb = qkvb;

  auto cvt = [&](const float* src, bf16* dst, int n) {
    int n4 = n >> 2;
    cvt_f32_bf16<<<dim3((n4 + 255) / 256), dim3(256), 0, stream>>>(src, dst, n4);
  };
  cvt(x, xb, NTOK * ND);
  cvt(wq, w3b, ND * ND);
  cvt(wk, w3b + ND * ND, ND * ND);
  cvt(wv, w3b + 2 * ND * ND, ND * ND);
  cvt(wfc, wfcb, ND * ND);
  cvt(w1f, w1fb, NDFF * ND);
  cvt(w2f, w2fb, ND * NDFF);
  concat3<<<dim3(1), dim3(512), 0, stream>>>(bq, bk, bv, b3);

  const dim3 blk(256);
  // fused QKV projection: [16384,1536] = x @ W3^T
  gemm_bt<false, false, true, false><<<dim3(LDQ / 128, NTOK / 128), blk, 0, stream>>>(
      xb, w3b, b3, nullptr, qkvb, nullptr, NTOK, LDQ, ND);
  // attention (writes AO = xb)
  attn_k<<<dim3(NB * NH, NS / 64), blk, 0, stream>>>(qkvb, AO, cur);
  // fc + residual(x) -> z (fp32)
  gemm_bt<false, true, false, true><<<dim3(ND / 128, NTOK / 128), blk, 0, stream>>>(
      AO, wfcb, bfc, x, nullptr, z, NTOK, ND, ND);
  // LN1: z -> z (fp32) + ln1bb (bf16)
  layernorm_k<<<dim3(NTOK / 4), blk, 0, stream>>>(z, ln1g, ln1b, 1e-5f, z, ln1bb);
  // FFN1 + ReLU -> hb (bf16)
  gemm_bt<true, false, true, false><<<dim3(NDFF / 128, NTOK / 128), blk, 0, stream>>>(
      ln1bb, w1fb, b1f, nullptr, hb, nullptr, NTOK, NDFF, ND);
  // FFN2 + residual(z) -> out (fp32)
  gemm_bt<false, true, false, true><<<dim3(ND / 128, NTOK / 128), blk, 0, stream>>>(
      hb, w2fb, b2f, z, nullptr, out, NTOK, ND, NDFF);
  // LN2 in place on out
  layernorm_k<<<dim3(NTOK / 4), blk, 0, stream>>>(out, ln2g, ln2b, 1e-6f, out, nullptr);
}